// Round 14
// baseline (80.888 us; speedup 1.0000x reference)
//
#include <hip/hip_runtime.h>

// ---------------------------------------------------------------------------
// Causal self-attention, B=4 T=4096 H=1024 D=64, fp32 in/out, bf16 MFMA inside.
// prep (weights->bf16) -> qkv GEMM -> fused flash attn + out-proj (R11 base).
// attn: grid 512 = 4b x 128 q-tiles(32 rows), complementary pairing; 256 thr
// = 4 waves = 4-way KV parity.  ILP-2 KV loop: each iteration processes TWO
// tiles (kt, kt+4) with one merged online-softmax update — independent QK^T /
// exp2 / PV streams amortize the per-tile dependency chain at 2 waves/SIMD.
// Separate accumulators o1/o2 (same m reference), summed before the merge.
// P^T in-register via v_cvt_pk_bf16_f32 + v_permlane32_swap_b32; defer-max.
// Fragment-native layouts for q/k/vT/Wo_b (all frag loads = 1KB wave-loads).
// ws usage: 6.5 MiB (Wall 384K | Wo_b 128K | q 2M | k 2M | vT 2M).
//
// Layouts (elements, per batch b):
//   q/k (t, d):  b*T*D + (t>>5)*2048 + (d>>4)*512 + (t&31)*16 + (d&15)
//   vT  (d, t):  b*D*T + (t>>6)*4096 + (d>>5)*2048 + ((t>>4)&3)*512
//                + (d&31)*16 + (t&15)
//   Wo_b(hcol,d): (hcol>>4)*1024 + (d>>5)*512 + (hcol&15)*32 + ((d>>3)&3)*8 + (d&7)
// ---------------------------------------------------------------------------

typedef __attribute__((ext_vector_type(4)))  float f32x4;
typedef __attribute__((ext_vector_type(16))) float f32x16;
typedef __attribute__((ext_vector_type(8)))  short s16x8;
typedef __attribute__((ext_vector_type(4)))  short s16x4;

#define DEV static __device__ __forceinline__

static constexpr int TT = 4096;        // sequence length
static constexpr int HH = 1024;        // hidden
static constexpr int DD = 64;          // head dim
static constexpr float MNEG = -3.0e38f; // finite -inf substitute (NaN-proof)

DEV unsigned short f2bf(float f) {     // round-to-nearest-even fp32->bf16
  union { float f; unsigned int u; } v; v.f = f;
  unsigned int r = v.u + 0x7FFFu + ((v.u >> 16) & 1u);
  return (unsigned short)(r >> 16);
}

DEV unsigned int cvtpk(float lo, float hi) {   // 2 bf16 in one u32 (HW RNE)
  unsigned int r;
  asm("v_cvt_pk_bf16_f32 %0, %1, %2" : "=v"(r) : "v"(lo), "v"(hi));
  return r;
}

DEV s16x8 mk8(unsigned int w0, unsigned int w1, unsigned int w2, unsigned int w3) {
  union { unsigned int u[4]; s16x8 v; } c;
  c.u[0] = w0; c.u[1] = w1; c.u[2] = w2; c.u[3] = w3; return c.v;
}

// XOR swizzles for 128B-row LDS tiles (bank-conflict avoidance)
DEV int swzA(int row) { return ((row & 7) << 4); }                     // 16-row tiles
DEV int swzK(int row) { return ((row & 7) << 4) ^ ((row & 8) << 3); }  // 32-row tiles

// ---------------------------------------------------------------------------
// Kernel 0: weights fp32 -> bf16.  Wall rows: [0,64)=Wq [64,128)=Wk [128,192)=Wv
// Wo_b written in proj-fragment layout.
// ---------------------------------------------------------------------------
__global__ void prep_kernel(const float* __restrict__ Wq, const float* __restrict__ Wk,
                            const float* __restrict__ Wv, const float* __restrict__ Wo,
                            unsigned short* __restrict__ Wall,
                            unsigned short* __restrict__ Wo_b)
{
  int i = blockIdx.x * blockDim.x + threadIdx.x;
  int stride = gridDim.x * blockDim.x;
  const int n1 = 64 * HH;
  for (int idx = i; idx < 3 * n1; idx += stride) {
    float v = idx < n1 ? Wq[idx] : (idx < 2 * n1 ? Wk[idx - n1] : Wv[idx - 2 * n1]);
    Wall[idx] = f2bf(v);
  }
  for (int idx = i; idx < HH * DD; idx += stride) {
    int hcol = idx >> 6, d = idx & 63;
    size_t off = (size_t)(hcol >> 4) * 1024 + (d >> 5) * 512 + (hcol & 15) * 32
               + ((d >> 3) & 3) * 8 + (d & 7);
    Wo_b[off] = f2bf(Wo[idx]);
  }
}

// ---------------------------------------------------------------------------
// Kernel 1: QKV projection.  512 blocks x 256 thr (2 blocks/CU); block = 32
// rows x 192 cols; K=1024 in 16 steps of 64.  Epilogue: acc -> LDS transpose
// -> contiguous 16B stores into fragment-native layouts.  q scaled log2e/8.
// ---------------------------------------------------------------------------
__global__ __launch_bounds__(256, 2) void qkv_kernel(
    const float* __restrict__ y, const unsigned short* __restrict__ Wall,
    const float* __restrict__ bq, const float* __restrict__ bk,
    const float* __restrict__ bv,
    unsigned short* __restrict__ q_ws, unsigned short* __restrict__ k_ws,
    unsigned short* __restrict__ vT_ws)
{
  __shared__ unsigned short ylds[2][32 * 64];
  __shared__ unsigned short wlds[2][192 * 64];
  const int t = threadIdx.x;
  const int wv = t >> 6, lane = t & 63, g = lane >> 4, c = lane & 15;
  const int row0 = blockIdx.x * 32;
  const int bb = row0 >> 12;
  const int tb = row0 & 4095;                  // 32-aligned
  const int yrow = t >> 3, ycol0 = (t & 7) * 8;

  f32x4 acc[2][3];
#pragma unroll
  for (int m = 0; m < 2; ++m)
#pragma unroll
    for (int i = 0; i < 3; ++i)
#pragma unroll
      for (int e = 0; e < 4; ++e) acc[m][i][e] = 0.0f;

  f32x4 yr[2];
  s16x8 wr[6];

  auto load_tiles = [&](int kb) {
    const float* src = y + (size_t)(row0 + yrow) * HH + kb * 64 + ycol0;
    yr[0] = *(const f32x4*)(src);
    yr[1] = *(const f32x4*)(src + 4);
#pragma unroll
    for (int ii = 0; ii < 6; ++ii) {
      int ch = t + ii * 256;
      int rw = ch >> 3, c0 = (ch & 7) * 8;
      wr[ii] = *(const s16x8*)(Wall + (size_t)rw * HH + kb * 64 + c0);
    }
  };
  auto write_tiles = [&](int buf) {
    s16x8 h0;
#pragma unroll
    for (int e = 0; e < 4; ++e) {
      h0[e]     = (short)f2bf(yr[0][e]);
      h0[e + 4] = (short)f2bf(yr[1][e]);
    }
    int byte0 = yrow * 128 + ycol0 * 2;
    *(s16x8*)((char*)ylds[buf] + (byte0 ^ swzA(yrow))) = h0;
#pragma unroll
    for (int ii = 0; ii < 6; ++ii) {
      int ch = t + ii * 256;
      int rw = ch >> 3, c0 = (ch & 7) * 8;
      int byte = rw * 128 + c0 * 2;
      *(s16x8*)((char*)wlds[buf] + (byte ^ swzA(rw))) = wr[ii];
    }
  };

  load_tiles(0);
  write_tiles(0);
  __syncthreads();
  for (int kb = 0; kb < 16; ++kb) {
    int buf = kb & 1;
    if (kb < 15) load_tiles(kb + 1);
#pragma unroll
    for (int kk = 0; kk < 2; ++kk) {
      s16x8 a[2], bfr[3];
#pragma unroll
      for (int m = 0; m < 2; ++m) {
        int ra = 16 * m + c;
        a[m] = *(const s16x8*)((char*)ylds[buf] +
                 ((ra * 128 + (kk * 32 + 8 * g) * 2) ^ swzA(ra)));
      }
#pragma unroll
      for (int i = 0; i < 3; ++i) {
        int rb = 16 * (3 * wv + i) + c;
        bfr[i] = *(const s16x8*)((char*)wlds[buf] +
                   ((rb * 128 + (kk * 32 + 8 * g) * 2) ^ swzA(rb)));
      }
#pragma unroll
      for (int m = 0; m < 2; ++m)
#pragma unroll
        for (int i = 0; i < 3; ++i)
          acc[m][i] = __builtin_amdgcn_mfma_f32_16x16x32_bf16(a[m], bfr[i], acc[m][i], 0, 0, 0);
    }
    __syncthreads();
    if (kb < 15) { write_tiles((kb + 1) & 1); __syncthreads(); }
  }

  // ---- epilogue: bias (+q scale) -> LDS [q 32x64, k 32x64, vT 64x32] ----
  unsigned short* elds = &wlds[0][0];     // 12,288 B alias (wlds dead)
  const float qsc = 1.4426950408889634f / 8.0f;   // log2e / sqrt(Dk)
#pragma unroll
  for (int m = 0; m < 2; ++m)
#pragma unroll
    for (int i = 0; i < 3; ++i) {
      int nt = 3 * wv + i;
      int sec = nt >> 2;
      int dcol = (nt & 3) * 16 + c;
      float bias = sec == 0 ? bq[dcol] : (sec == 1 ? bk[dcol] : bv[dcol]);
#pragma unroll
      for (int i2 = 0; i2 < 4; ++i2) {
        int rl = 16 * m + 4 * g + i2;
        float val = acc[m][i][i2] + bias;
        if (sec == 0) val *= qsc;
        if (sec < 2) elds[sec * 2048 + rl * 64 + dcol] = f2bf(val);
        else         elds[4096 + dcol * 32 + rl]       = f2bf(val);
      }
    }
  __syncthreads();
  // ---- contiguous 16B stores into fragment-native global layouts ----
  {
    int trow = t >> 3, d0 = (t & 7) * 8;           // q,k assignment
    s16x8 vq = *(const s16x8*)(elds + trow * 64 + d0);
    s16x8 vk = *(const s16x8*)(elds + 2048 + trow * 64 + d0);
    size_t offqk = (size_t)bb * (TT * DD) + (size_t)(tb >> 5) * 2048
                 + (d0 >> 4) * 512 + trow * 16 + (d0 & 15);
    *(s16x8*)(q_ws + offqk) = vq;
    *(s16x8*)(k_ws + offqk) = vk;
    int d = t >> 2, tq = (t & 3) * 8;              // v assignment
    s16x8 vvv = *(const s16x8*)(elds + 4096 + d * 32 + tq);
    int tg = tb + tq;
    size_t offv = (size_t)bb * (DD * TT) + (size_t)(tg >> 6) * 4096
                + (d >> 5) * 2048 + ((tg >> 4) & 3) * 512 + (d & 31) * 16 + (tg & 15);
    *(s16x8*)(vT_ws + offv) = vvv;
  }
}

// ---------------------------------------------------------------------------
// Kernel 2: fused flash attention + output projection (ILP-2 KV loop).
// Grid 512 = 4 b x 128 q-tiles(32 rows); complementary pairing j32(s).
// 4 waves = 4-way KV parity; each iteration covers tiles kt and kt+4.
// ---------------------------------------------------------------------------
__global__ __launch_bounds__(256, 2) void attn_kernel(
    const unsigned short* __restrict__ q_ws, const unsigned short* __restrict__ k_ws,
    const unsigned short* __restrict__ vT_ws, const unsigned short* __restrict__ Wo_b,
    const float* __restrict__ bo, float* __restrict__ out)
{
  __shared__ float obuf[3 * 2048];          // waves 1-3 O^T          (24 KB)
  __shared__ float mstat[3 * 128];          // waves 1-3 m,l          (1.5 KB)
  __shared__ unsigned short clds[32 * 64];  // merged ctx bf16 [q][d] (4 KB)
  const int t = threadIdx.x, wv = t >> 6, lane = t & 63;
  const int qcol = lane & 31, h = lane >> 5;
  const int b = blockIdx.x & 3;
  const int jslot = blockIdx.x >> 2;
  const int j32 = (jslot < 64) ? (2 * jslot) : (127 - 2 * (jslot - 64));
  const int q0 = j32 * 32;
  const int L = j32 >> 1;                   // last KV tile (diagonal)
  const size_t base  = (size_t)b * TT * DD; // q,k frag space
  const size_t vbase = (size_t)b * DD * TT; // vT frag space
  const int g = lane >> 4, c = lane & 15;   // proj phase
  const int lchunk = (lane & 31) * 16 + (lane >> 5) * 8;   // frag lane offset

  // Q B-frags (contiguous 1KB per kk)
  s16x8 qf[4];
  {
    const unsigned short* qp = q_ws + base + (size_t)j32 * 2048;
#pragma unroll
    for (int kk = 0; kk < 4; ++kk) qf[kk] = *(const s16x8*)(qp + kk * 512 + lchunk);
  }
  f32x16 o1[2], o2[2];                      // per-tile-stream accumulators
#pragma unroll
  for (int mt = 0; mt < 2; ++mt)
#pragma unroll
    for (int rg = 0; rg < 16; ++rg) { o1[mt][rg] = 0.0f; o2[mt][rg] = 0.0f; }
  float m_run = MNEG, l_run = 0.0f;

  auto loadK = [&](int kt, s16x8 (&kf)[2][4]) {
#pragma unroll
    for (int mt = 0; mt < 2; ++mt)
#pragma unroll
      for (int kk = 0; kk < 4; ++kk)
        kf[mt][kk] = *(const s16x8*)(k_ws + base +
                       (size_t)(2 * kt + mt) * 2048 + kk * 512 + lchunk);
  };
  auto loadV = [&](int kt, s16x8 (&vf)[2][4]) {
#pragma unroll
    for (int mt = 0; mt < 2; ++mt)
#pragma unroll
      for (int ks = 0; ks < 4; ++ks)
        vf[mt][ks] = *(const s16x8*)(vT_ws + vbase +
                       (size_t)kt * 4096 + mt * 2048 + ks * 512 + lchunk);
  };
  auto qk = [&](const s16x8 (&kf)[2][4], f32x16 (&s)[2]) {
#pragma unroll
    for (int mt = 0; mt < 2; ++mt)
#pragma unroll
      for (int rg = 0; rg < 16; ++rg) s[mt][rg] = 0.0f;
#pragma unroll
    for (int kk = 0; kk < 4; ++kk)
#pragma unroll
      for (int mt = 0; mt < 2; ++mt)
        s[mt] = __builtin_amdgcn_mfma_f32_32x32x16_bf16(kf[mt][kk], qf[kk], s[mt], 0, 0, 0);
  };
  auto mask = [&](int kt, f32x16 (&s)[2]) {
    int qq = q0 + qcol;
#pragma unroll
    for (int mt = 0; mt < 2; ++mt)
#pragma unroll
      for (int rg = 0; rg < 16; ++rg) {
        int kvabs = kt * 64 + 32 * mt + (rg & 3) + 8 * (rg >> 2) + 4 * h;
        if (kvabs > qq) s[mt][rg] = MNEG;
      }
  };
  auto treemax = [&](const f32x16 (&s)[2]) {
    float mx[16];
#pragma unroll
    for (int e = 0; e < 16; ++e) mx[e] = fmaxf(s[0][e], s[1][e]);
#pragma unroll
    for (int st = 8; st >= 1; st >>= 1)
#pragma unroll
      for (int e = 0; e < 8; ++e) if (e < st) mx[e] = fmaxf(mx[e], mx[e + st]);
    return mx[0];
  };
  auto expsum = [&](f32x16 (&s)[2], float m_new) {
#pragma unroll
    for (int mt = 0; mt < 2; ++mt)
#pragma unroll
      for (int rg = 0; rg < 16; ++rg) s[mt][rg] = exp2f(s[mt][rg] - m_new);
    float sm[16];
#pragma unroll
    for (int e = 0; e < 16; ++e) sm[e] = s[0][e] + s[1][e];
#pragma unroll
    for (int st = 8; st >= 1; st >>= 1)
#pragma unroll
      for (int e = 0; e < 8; ++e) if (e < st) sm[e] += sm[e + st];
    return sm[0];
  };
  auto pack = [&](const f32x16 (&s)[2], s16x8 (&pf)[4]) {
#pragma unroll
    for (int mt = 0; mt < 2; ++mt) {
      unsigned int a0 = cvtpk(s[mt][0],  s[mt][1]);
      unsigned int a1 = cvtpk(s[mt][2],  s[mt][3]);
      unsigned int b0 = cvtpk(s[mt][4],  s[mt][5]);
      unsigned int b1 = cvtpk(s[mt][6],  s[mt][7]);
      unsigned int c0 = cvtpk(s[mt][8],  s[mt][9]);
      unsigned int c1 = cvtpk(s[mt][10], s[mt][11]);
      unsigned int d0 = cvtpk(s[mt][12], s[mt][13]);
      unsigned int d1 = cvtpk(s[mt][14], s[mt][15]);
      asm("v_permlane32_swap_b32 %0, %1" : "+v"(a0), "+v"(b0));
      asm("v_permlane32_swap_b32 %0, %1" : "+v"(a1), "+v"(b1));
      asm("v_permlane32_swap_b32 %0, %1" : "+v"(c0), "+v"(d0));
      asm("v_permlane32_swap_b32 %0, %1" : "+v"(c1), "+v"(d1));
      pf[2 * mt]     = mk8(a0, a1, b0, b1);
      pf[2 * mt + 1] = mk8(c0, c1, d0, d1);
    }
  };
  auto pv = [&](const s16x8 (&vf)[2][4], const s16x8 (&pf)[4], f32x16 (&o)[2]) {
#pragma unroll
    for (int ks = 0; ks < 4; ++ks)
#pragma unroll
      for (int mt = 0; mt < 2; ++mt)
        o[mt] = __builtin_amdgcn_mfma_f32_32x32x16_bf16(vf[mt][ks], pf[ks], o[mt], 0, 0, 0);
  };

  for (int kt = wv; kt <= L; kt += 8) {
    const int kt2 = kt + 4;
    const bool has2 = (kt2 <= L);            // wave-uniform
    // ---- loads for both tiles (independent streams) ----
    s16x8 kf1[2][4], kf2[2][4];
    loadK(kt, kf1);
    if (has2) loadK(kt2, kf2);
    // ---- QK^T both tiles ----
    f32x16 s1[2], s2[2];
    __builtin_amdgcn_s_setprio(1);
    qk(kf1, s1);
    if (has2) qk(kf2, s2);
    __builtin_amdgcn_s_setprio(0);
    // ---- V loads (independent of softmax; hidden under it) ----
    s16x8 vf1[2][4], vf2[2][4];
    loadV(kt, vf1);
    if (has2) loadV(kt2, vf2);
    // ---- masks ----
    if (kt == L) mask(kt, s1);
    if (has2 && kt2 == L) mask(kt2, s2);
    // ---- merged online softmax ----
    float pm = treemax(s1);
    if (has2) pm = fmaxf(pm, treemax(s2));
    pm = fmaxf(pm, __shfl_xor(pm, 32));      // REQUIRED: other h-half
    float m_new;
    if (__all(pm - m_run <= 8.0f)) {         // defer-max
      m_new = m_run;
    } else {
      m_new = fmaxf(m_run, pm);
      float alpha = exp2f(m_run - m_new);
      l_run *= alpha;
#pragma unroll
      for (int mt = 0; mt < 2; ++mt)
#pragma unroll
        for (int rg = 0; rg < 16; ++rg) { o1[mt][rg] *= alpha; o2[mt][rg] *= alpha; }
      m_run = m_new;
    }
    float rowsum = expsum(s1, m_new);
    if (has2) rowsum += expsum(s2, m_new);
    rowsum += __shfl_xor(rowsum, 32);        // REQUIRED: other h-half
    l_run += rowsum;
    // ---- pack + PV both tiles (o1/o2 = independent MFMA chains) ----
    s16x8 pf1[4], pf2[4];
    pack(s1, pf1);
    if (has2) pack(s2, pf2);
    __builtin_amdgcn_s_setprio(1);
    pv(vf1, pf1, o1);
    if (has2) pv(vf2, pf2, o2);
    __builtin_amdgcn_s_setprio(0);
  }

  // ---- combine tile streams (same m reference) ----
  f32x16 o[2];
#pragma unroll
  for (int mt = 0; mt < 2; ++mt)
#pragma unroll
    for (int rg = 0; rg < 16; ++rg) o[mt][rg] = o1[mt][rg] + o2[mt][rg];

  // ---- 4-way flash merge (wave 0 combines), ctx -> LDS bf16 [q][d] ----
  if (wv != 0) {
#pragma unroll
    for (int mt = 0; mt < 2; ++mt)
#pragma unroll
      for (int rg = 0; rg < 16; ++rg)
        obuf[(wv - 1) * 2048 + (mt * 16 + rg) * 64 + lane] = o[mt][rg];
    mstat[(wv - 1) * 128 + lane] = m_run;
    mstat[(wv - 1) * 128 + 64 + lane] = l_run;
  }
  __syncthreads();
  if (wv == 0) {
    float mB[3], lB[3];
    float mS = m_run;
#pragma unroll
    for (int i = 0; i < 3; ++i) {
      mB[i] = mstat[i * 128 + lane];
      lB[i] = mstat[i * 128 + 64 + lane];
      mS = fmaxf(mS, mB[i]);
    }
    float f0 = exp2f(m_run - mS);
    float fi[3];
    float l_tot = l_run * f0;
#pragma unroll
    for (int i = 0; i < 3; ++i) { fi[i] = exp2f(mB[i] - mS); l_tot += lB[i] * fi[i]; }
    float inv = 1.0f / l_tot;
#pragma unroll
    for (int mt = 0; mt < 2; ++mt) {
#pragma unroll
      for (int rgq = 0; rgq < 4; ++rgq) {
        s16x4 pb;
#pragma unroll
        for (int e = 0; e < 4; ++e) {
          int rg = 4 * rgq + e;
          float val = o[mt][rg] * f0;
#pragma unroll
          for (int i = 0; i < 3; ++i)
            val += obuf[i * 2048 + (mt * 16 + rg) * 64 + lane] * fi[i];
          pb[e] = (short)f2bf(val * inv);
        }
        int d0 = 32 * mt + 8 * rgq + 4 * h;
        int byte = qcol * 128 + d0 * 2;
        *(s16x4*)((char*)clds + (byte ^ swzK(qcol))) = pb;
      }
    }
  }
  __syncthreads();

  // ---- fused output projection: out[q0..q0+32) x 1024 = ctx(32x64) . Wo^T ----
  s16x8 afr[2][2];
#pragma unroll
  for (int mt = 0; mt < 2; ++mt)
#pragma unroll
    for (int kk = 0; kk < 2; ++kk) {
      int ra = 16 * mt + c;
      afr[mt][kk] = *(const s16x8*)((char*)clds +
                      ((ra * 128 + (32 * kk + 8 * g) * 2) ^ swzK(ra)));
    }
  const int wchunk = (lane & 15) * 32 + (lane >> 4) * 8;   // Wo_b frag lane offset
  const size_t orow0 = (size_t)(b * TT + q0);
#pragma unroll 4
  for (int nt = 0; nt < 16; ++nt) {
    int col = wv * 256 + 16 * nt + c;
    s16x8 bfr[2];
#pragma unroll
    for (int kk = 0; kk < 2; ++kk)
      bfr[kk] = *(const s16x8*)(Wo_b + (size_t)(wv * 16 + nt) * 1024
                                + kk * 512 + wchunk);
    f32x4 acc4[2];
#pragma unroll
    for (int mt = 0; mt < 2; ++mt)
#pragma unroll
      for (int e = 0; e < 4; ++e) acc4[mt][e] = 0.0f;
#pragma unroll
    for (int kk = 0; kk < 2; ++kk)
#pragma unroll
      for (int mt = 0; mt < 2; ++mt)
        acc4[mt] = __builtin_amdgcn_mfma_f32_16x16x32_bf16(afr[mt][kk], bfr[kk],
                                                           acc4[mt], 0, 0, 0);
    float bias = bo[col];
#pragma unroll
    for (int mt = 0; mt < 2; ++mt)
#pragma unroll
      for (int i = 0; i < 4; ++i) {
        size_t row = orow0 + 16 * mt + 4 * g + i;
        out[row * HH + col] = acc4[mt][i] + bias;
      }
  }
}

// ---------------------------------------------------------------------------
extern "C" void kernel_launch(void* const* d_in, const int* in_sizes, int n_in,
                              void* d_out, int out_size, void* d_ws, size_t ws_size,
                              hipStream_t stream)
{
  const float* y  = (const float*)d_in[0];
  const float* Wq = (const float*)d_in[1];
  const float* bq = (const float*)d_in[2];
  const float* Wk = (const float*)d_in[3];
  const float* bk = (const float*)d_in[4];
  const float* Wv = (const float*)d_in[5];
  const float* bv = (const float*)d_in[6];
  const float* Wo = (const float*)d_in[7];
  const float* bo = (const float*)d_in[8];
  float* out = (float*)d_out;
  char* ws = (char*)d_ws;
  // workspace layout (bytes) — total 6,815,744 (6.5 MiB)
  unsigned short* Wall  = (unsigned short*)(ws);                        // 384 KiB
  unsigned short* Wo_b  = (unsigned short*)(ws + 393216);               // 128 KiB
  unsigned short* q_ws  = (unsigned short*)(ws + 524288);               // 2 MiB
  unsigned short* k_ws  = (unsigned short*)(ws + 524288 + 2097152);     // 2 MiB
  unsigned short* vT_ws = (unsigned short*)(ws + 524288 + 2 * 2097152); // 2 MiB

  prep_kernel<<<dim3(256), dim3(256), 0, stream>>>(Wq, Wk, Wv, Wo, Wall, Wo_b);
  qkv_kernel<<<dim3(512), dim3(256), 0, stream>>>(y, Wall, bq, bk, bv, q_ws, k_ws, vT_ws);
  attn_kernel<<<dim3(512), dim3(256), 0, stream>>>(q_ws, k_ws, vT_ws, Wo_b, bo, out);
}

// Round 15
// 58.133 us; speedup vs baseline: 1.3914x; 1.3914x over previous
//
#include <hip/hip_runtime.h>

// ---------------------------------------------------------------------------
// Causal self-attention, B=4 T=4096 H=1024 D=64, fp32 in/out, bf16 MFMA inside.
// prep (weights->bf16) -> qkv GEMM (512x32-row blocks, LDS-transpose epilogue)
// -> fused flash attn + out-proj (R11 configuration, best measured 58.4us):
//   grid 512 = 4 b x 128 q-tiles(32 rows), complementary pairing;
//   block = 256 thr = 4 waves = 4-way KV parity; __launch_bounds__(256,2).
// P^T in-register via v_cvt_pk_bf16_f32 + v_permlane32_swap_b32; defer-max.
// Fragment-native layouts for q/k/vT/Wo_b (all frag loads = 1KB wave-loads).
// ws usage: 6.5 MiB (Wall 384K | Wo_b 128K | q 2M | k 2M | vT 2M).
//
// Layouts (elements, per batch b):
//   q/k (t, d):  b*T*D + (t>>5)*2048 + (d>>4)*512 + (t&31)*16 + (d&15)
//   vT  (d, t):  b*D*T + (t>>6)*4096 + (d>>5)*2048 + ((t>>4)&3)*512
//                + (d&31)*16 + (t&15)
//   Wo_b(hcol,d): (hcol>>4)*1024 + (d>>5)*512 + (hcol&15)*32 + ((d>>3)&3)*8 + (d&7)
// ---------------------------------------------------------------------------

typedef __attribute__((ext_vector_type(4)))  float f32x4;
typedef __attribute__((ext_vector_type(16))) float f32x16;
typedef __attribute__((ext_vector_type(8)))  short s16x8;
typedef __attribute__((ext_vector_type(4)))  short s16x4;

#define DEV static __device__ __forceinline__

static constexpr int TT = 4096;        // sequence length
static constexpr int HH = 1024;        // hidden
static constexpr int DD = 64;          // head dim
static constexpr float MNEG = -3.0e38f; // finite -inf substitute (NaN-proof)

DEV unsigned short f2bf(float f) {     // round-to-nearest-even fp32->bf16
  union { float f; unsigned int u; } v; v.f = f;
  unsigned int r = v.u + 0x7FFFu + ((v.u >> 16) & 1u);
  return (unsigned short)(r >> 16);
}

DEV unsigned int cvtpk(float lo, float hi) {   // 2 bf16 in one u32 (HW RNE)
  unsigned int r;
  asm("v_cvt_pk_bf16_f32 %0, %1, %2" : "=v"(r) : "v"(lo), "v"(hi));
  return r;
}

DEV s16x8 mk8(unsigned int w0, unsigned int w1, unsigned int w2, unsigned int w3) {
  union { unsigned int u[4]; s16x8 v; } c;
  c.u[0] = w0; c.u[1] = w1; c.u[2] = w2; c.u[3] = w3; return c.v;
}

// XOR swizzles for 128B-row LDS tiles (bank-conflict avoidance)
DEV int swzA(int row) { return ((row & 7) << 4); }                     // 16-row tiles
DEV int swzK(int row) { return ((row & 7) << 4) ^ ((row & 8) << 3); }  // 32-row tiles

// ---------------------------------------------------------------------------
// Kernel 0: weights fp32 -> bf16.  Wall rows: [0,64)=Wq [64,128)=Wk [128,192)=Wv
// Wo_b written in proj-fragment layout.
// ---------------------------------------------------------------------------
__global__ void prep_kernel(const float* __restrict__ Wq, const float* __restrict__ Wk,
                            const float* __restrict__ Wv, const float* __restrict__ Wo,
                            unsigned short* __restrict__ Wall,
                            unsigned short* __restrict__ Wo_b)
{
  int i = blockIdx.x * blockDim.x + threadIdx.x;
  int stride = gridDim.x * blockDim.x;
  const int n1 = 64 * HH;
  for (int idx = i; idx < 3 * n1; idx += stride) {
    float v = idx < n1 ? Wq[idx] : (idx < 2 * n1 ? Wk[idx - n1] : Wv[idx - 2 * n1]);
    Wall[idx] = f2bf(v);
  }
  for (int idx = i; idx < HH * DD; idx += stride) {
    int hcol = idx >> 6, d = idx & 63;
    size_t off = (size_t)(hcol >> 4) * 1024 + (d >> 5) * 512 + (hcol & 15) * 32
               + ((d >> 3) & 3) * 8 + (d & 7);
    Wo_b[off] = f2bf(Wo[idx]);
  }
}

// ---------------------------------------------------------------------------
// Kernel 1: QKV projection.  512 blocks x 256 thr (2 blocks/CU); block = 32
// rows x 192 cols; K=1024 in 16 steps of 64.  Epilogue: acc -> LDS transpose
// -> contiguous 16B stores into fragment-native layouts.  q scaled log2e/8.
// ---------------------------------------------------------------------------
__global__ __launch_bounds__(256, 2) void qkv_kernel(
    const float* __restrict__ y, const unsigned short* __restrict__ Wall,
    const float* __restrict__ bq, const float* __restrict__ bk,
    const float* __restrict__ bv,
    unsigned short* __restrict__ q_ws, unsigned short* __restrict__ k_ws,
    unsigned short* __restrict__ vT_ws)
{
  __shared__ unsigned short ylds[2][32 * 64];
  __shared__ unsigned short wlds[2][192 * 64];
  const int t = threadIdx.x;
  const int wv = t >> 6, lane = t & 63, g = lane >> 4, c = lane & 15;
  const int row0 = blockIdx.x * 32;
  const int bb = row0 >> 12;
  const int tb = row0 & 4095;                  // 32-aligned
  const int yrow = t >> 3, ycol0 = (t & 7) * 8;

  f32x4 acc[2][3];
#pragma unroll
  for (int m = 0; m < 2; ++m)
#pragma unroll
    for (int i = 0; i < 3; ++i)
#pragma unroll
      for (int e = 0; e < 4; ++e) acc[m][i][e] = 0.0f;

  f32x4 yr[2];
  s16x8 wr[6];

  auto load_tiles = [&](int kb) {
    const float* src = y + (size_t)(row0 + yrow) * HH + kb * 64 + ycol0;
    yr[0] = *(const f32x4*)(src);
    yr[1] = *(const f32x4*)(src + 4);
#pragma unroll
    for (int ii = 0; ii < 6; ++ii) {
      int ch = t + ii * 256;
      int rw = ch >> 3, c0 = (ch & 7) * 8;
      wr[ii] = *(const s16x8*)(Wall + (size_t)rw * HH + kb * 64 + c0);
    }
  };
  auto write_tiles = [&](int buf) {
    s16x8 h0;
#pragma unroll
    for (int e = 0; e < 4; ++e) {
      h0[e]     = (short)f2bf(yr[0][e]);
      h0[e + 4] = (short)f2bf(yr[1][e]);
    }
    int byte0 = yrow * 128 + ycol0 * 2;
    *(s16x8*)((char*)ylds[buf] + (byte0 ^ swzA(yrow))) = h0;
#pragma unroll
    for (int ii = 0; ii < 6; ++ii) {
      int ch = t + ii * 256;
      int rw = ch >> 3, c0 = (ch & 7) * 8;
      int byte = rw * 128 + c0 * 2;
      *(s16x8*)((char*)wlds[buf] + (byte ^ swzA(rw))) = wr[ii];
    }
  };

  load_tiles(0);
  write_tiles(0);
  __syncthreads();
  for (int kb = 0; kb < 16; ++kb) {
    int buf = kb & 1;
    if (kb < 15) load_tiles(kb + 1);
#pragma unroll
    for (int kk = 0; kk < 2; ++kk) {
      s16x8 a[2], bfr[3];
#pragma unroll
      for (int m = 0; m < 2; ++m) {
        int ra = 16 * m + c;
        a[m] = *(const s16x8*)((char*)ylds[buf] +
                 ((ra * 128 + (kk * 32 + 8 * g) * 2) ^ swzA(ra)));
      }
#pragma unroll
      for (int i = 0; i < 3; ++i) {
        int rb = 16 * (3 * wv + i) + c;
        bfr[i] = *(const s16x8*)((char*)wlds[buf] +
                   ((rb * 128 + (kk * 32 + 8 * g) * 2) ^ swzA(rb)));
      }
#pragma unroll
      for (int m = 0; m < 2; ++m)
#pragma unroll
        for (int i = 0; i < 3; ++i)
          acc[m][i] = __builtin_amdgcn_mfma_f32_16x16x32_bf16(a[m], bfr[i], acc[m][i], 0, 0, 0);
    }
    __syncthreads();
    if (kb < 15) { write_tiles((kb + 1) & 1); __syncthreads(); }
  }

  // ---- epilogue: bias (+q scale) -> LDS [q 32x64, k 32x64, vT 64x32] ----
  unsigned short* elds = &wlds[0][0];     // 12,288 B alias (wlds dead)
  const float qsc = 1.4426950408889634f / 8.0f;   // log2e / sqrt(Dk)
#pragma unroll
  for (int m = 0; m < 2; ++m)
#pragma unroll
    for (int i = 0; i < 3; ++i) {
      int nt = 3 * wv + i;
      int sec = nt >> 2;
      int dcol = (nt & 3) * 16 + c;
      float bias = sec == 0 ? bq[dcol] : (sec == 1 ? bk[dcol] : bv[dcol]);
#pragma unroll
      for (int i2 = 0; i2 < 4; ++i2) {
        int rl = 16 * m + 4 * g + i2;
        float val = acc[m][i][i2] + bias;
        if (sec == 0) val *= qsc;
        if (sec < 2) elds[sec * 2048 + rl * 64 + dcol] = f2bf(val);
        else         elds[4096 + dcol * 32 + rl]       = f2bf(val);
      }
    }
  __syncthreads();
  // ---- contiguous 16B stores into fragment-native global layouts ----
  {
    int trow = t >> 3, d0 = (t & 7) * 8;           // q,k assignment
    s16x8 vq = *(const s16x8*)(elds + trow * 64 + d0);
    s16x8 vk = *(const s16x8*)(elds + 2048 + trow * 64 + d0);
    size_t offqk = (size_t)bb * (TT * DD) + (size_t)(tb >> 5) * 2048
                 + (d0 >> 4) * 512 + trow * 16 + (d0 & 15);
    *(s16x8*)(q_ws + offqk) = vq;
    *(s16x8*)(k_ws + offqk) = vk;
    int d = t >> 2, tq = (t & 3) * 8;              // v assignment
    s16x8 vvv = *(const s16x8*)(elds + 4096 + d * 32 + tq);
    int tg = tb + tq;
    size_t offv = (size_t)bb * (DD * TT) + (size_t)(tg >> 6) * 4096
                + (d >> 5) * 2048 + ((tg >> 4) & 3) * 512 + (d & 31) * 16 + (tg & 15);
    *(s16x8*)(vT_ws + offv) = vvv;
  }
}

// ---------------------------------------------------------------------------
// Kernel 2: fused flash attention + output projection.
// Grid 512 = 4 b x 128 q-tiles(32 rows); complementary pairing j32(s).
// 4 waves = 4-way KV parity, fully independent until the final merge.
// All fragment loads are contiguous 1KB wave-loads (fragment-native layouts).
// S^T = K.Q^T (32x32x16); per-lane softmax + shfl_xor(32) h-half combine;
// defer-max; P^T via cvt_pk_bf16 + permlane32_swap (24 ops vs ~150).
// O^T += V^T.P^T; 4-way merge (fp32 obuf); fused 32x1024 out-proj.
// ---------------------------------------------------------------------------
__global__ __launch_bounds__(256, 2) void attn_kernel(
    const unsigned short* __restrict__ q_ws, const unsigned short* __restrict__ k_ws,
    const unsigned short* __restrict__ vT_ws, const unsigned short* __restrict__ Wo_b,
    const float* __restrict__ bo, float* __restrict__ out)
{
  __shared__ float obuf[3 * 2048];          // waves 1-3 O^T          (24 KB)
  __shared__ float mstat[3 * 128];          // waves 1-3 m,l          (1.5 KB)
  __shared__ unsigned short clds[32 * 64];  // merged ctx bf16 [q][d] (4 KB)
  const int t = threadIdx.x, wv = t >> 6, lane = t & 63;
  const int qcol = lane & 31, h = lane >> 5;
  const int b = blockIdx.x & 3;
  const int jslot = blockIdx.x >> 2;
  const int j32 = (jslot < 64) ? (2 * jslot) : (127 - 2 * (jslot - 64));
  const int q0 = j32 * 32;
  const int L = j32 >> 1;                   // last KV tile (diagonal)
  const size_t base  = (size_t)b * TT * DD; // q,k frag space
  const size_t vbase = (size_t)b * DD * TT; // vT frag space
  const int g = lane >> 4, c = lane & 15;   // proj phase
  const int lchunk = (lane & 31) * 16 + (lane >> 5) * 8;   // frag lane offset

  // Q B-frags (contiguous 1KB per kk)
  s16x8 qf[4];
  {
    const unsigned short* qp = q_ws + base + (size_t)j32 * 2048;
#pragma unroll
    for (int kk = 0; kk < 4; ++kk) qf[kk] = *(const s16x8*)(qp + kk * 512 + lchunk);
  }
  f32x16 o[2];
#pragma unroll
  for (int mt = 0; mt < 2; ++mt)
#pragma unroll
    for (int rg = 0; rg < 16; ++rg) o[mt][rg] = 0.0f;
  float m_run = MNEG, l_run = 0.0f;

  for (int kt = wv; kt <= L; kt += 4) {
    const int kv0 = kt * 64;
    // ---- K A-frags: contiguous 1KB wave-loads ----
    s16x8 kf[2][4];
#pragma unroll
    for (int mt = 0; mt < 2; ++mt)
#pragma unroll
      for (int kk = 0; kk < 4; ++kk)
        kf[mt][kk] = *(const s16x8*)(k_ws + base +
                       (size_t)(2 * kt + mt) * 2048 + kk * 512 + lchunk);
    // ---- S^T = K . Q^T ----
    f32x16 s[2];
#pragma unroll
    for (int mt = 0; mt < 2; ++mt)
#pragma unroll
      for (int rg = 0; rg < 16; ++rg) s[mt][rg] = 0.0f;
    __builtin_amdgcn_s_setprio(1);
#pragma unroll
    for (int kk = 0; kk < 4; ++kk)
#pragma unroll
      for (int mt = 0; mt < 2; ++mt)
        s[mt] = __builtin_amdgcn_mfma_f32_32x32x16_bf16(kf[mt][kk], qf[kk], s[mt], 0, 0, 0);
    __builtin_amdgcn_s_setprio(0);
    // ---- V^T A-frags (issued early; consumed after softmax) ----
    s16x8 vf[2][4];
#pragma unroll
    for (int mt = 0; mt < 2; ++mt)
#pragma unroll
      for (int ks = 0; ks < 4; ++ks)
        vf[mt][ks] = *(const s16x8*)(vT_ws + vbase +
                       (size_t)kt * 4096 + mt * 2048 + ks * 512 + lchunk);
    // ---- causal mask (diagonal tile only) ----
    if (kt == L) {
      int qq = q0 + qcol;
#pragma unroll
      for (int mt = 0; mt < 2; ++mt)
#pragma unroll
        for (int rg = 0; rg < 16; ++rg) {
          int kvabs = kv0 + 32 * mt + (rg & 3) + 8 * (rg >> 2) + 4 * h;
          if (kvabs > qq) s[mt][rg] = MNEG;
        }
    }
    // ---- online softmax (log2 domain): per-lane tree + cross-half shfl ----
    float mx[16];
#pragma unroll
    for (int e = 0; e < 16; ++e) mx[e] = fmaxf(s[0][e], s[1][e]);
#pragma unroll
    for (int st = 8; st >= 1; st >>= 1)
#pragma unroll
      for (int e = 0; e < 8; ++e) if (e < st) mx[e] = fmaxf(mx[e], mx[e + st]);
    float pm = fmaxf(mx[0], __shfl_xor(mx[0], 32));   // REQUIRED: other h-half
    float m_new;
    if (__all(pm - m_run <= 8.0f)) {      // defer-max: keep stale m (P <= 2^8)
      m_new = m_run;
    } else {
      m_new = fmaxf(m_run, pm);
      float alpha = exp2f(m_run - m_new);
      l_run *= alpha;
#pragma unroll
      for (int mt = 0; mt < 2; ++mt)
#pragma unroll
        for (int rg = 0; rg < 16; ++rg) o[mt][rg] *= alpha;
      m_run = m_new;
    }
#pragma unroll
    for (int mt = 0; mt < 2; ++mt)
#pragma unroll
      for (int rg = 0; rg < 16; ++rg) s[mt][rg] = exp2f(s[mt][rg] - m_new);
    float sm[16];
#pragma unroll
    for (int e = 0; e < 16; ++e) sm[e] = s[0][e] + s[1][e];
#pragma unroll
    for (int st = 8; st >= 1; st >>= 1)
#pragma unroll
      for (int e = 0; e < 8; ++e) if (e < st) sm[e] += sm[e + st];
    float rowsum = sm[0] + __shfl_xor(sm[0], 32);     // REQUIRED: other h-half
    l_run += rowsum;
    // ---- pack P^T B-frags: cvt_pk pairs + permlane32_swap (T12) ----
    s16x8 pf[4];
#pragma unroll
    for (int mt = 0; mt < 2; ++mt) {
      unsigned int a0 = cvtpk(s[mt][0],  s[mt][1]);   // kv 4h+0,1
      unsigned int a1 = cvtpk(s[mt][2],  s[mt][3]);   // kv 4h+2,3
      unsigned int b0 = cvtpk(s[mt][4],  s[mt][5]);   // kv 8+4h+0,1
      unsigned int b1 = cvtpk(s[mt][6],  s[mt][7]);   // kv 8+4h+2,3
      unsigned int c0 = cvtpk(s[mt][8],  s[mt][9]);   // kv 16+4h+0,1
      unsigned int c1 = cvtpk(s[mt][10], s[mt][11]);  // kv 16+4h+2,3
      unsigned int d0 = cvtpk(s[mt][12], s[mt][13]);  // kv 24+4h+0,1
      unsigned int d1 = cvtpk(s[mt][14], s[mt][15]);  // kv 24+4h+2,3
      asm("v_permlane32_swap_b32 %0, %1" : "+v"(a0), "+v"(b0));
      asm("v_permlane32_swap_b32 %0, %1" : "+v"(a1), "+v"(b1));
      asm("v_permlane32_swap_b32 %0, %1" : "+v"(c0), "+v"(d0));
      asm("v_permlane32_swap_b32 %0, %1" : "+v"(c1), "+v"(d1));
      pf[2 * mt]     = mk8(a0, a1, b0, b1);
      pf[2 * mt + 1] = mk8(c0, c1, d0, d1);
    }
    // ---- O^T += V^T . P^T ----
    __builtin_amdgcn_s_setprio(1);
#pragma unroll
    for (int ks = 0; ks < 4; ++ks)
#pragma unroll
      for (int mt = 0; mt < 2; ++mt)
        o[mt] = __builtin_amdgcn_mfma_f32_32x32x16_bf16(vf[mt][ks], pf[ks], o[mt], 0, 0, 0);
    __builtin_amdgcn_s_setprio(0);
  }

  // ---- 4-way flash merge (wave 0 combines), ctx -> LDS bf16 [q][d] ----
  if (wv != 0) {
#pragma unroll
    for (int mt = 0; mt < 2; ++mt)
#pragma unroll
      for (int rg = 0; rg < 16; ++rg)
        obuf[(wv - 1) * 2048 + (mt * 16 + rg) * 64 + lane] = o[mt][rg];
    mstat[(wv - 1) * 128 + lane] = m_run;
    mstat[(wv - 1) * 128 + 64 + lane] = l_run;
  }
  __syncthreads();
  if (wv == 0) {
    float mB[3], lB[3];
    float mS = m_run;
#pragma unroll
    for (int i = 0; i < 3; ++i) {
      mB[i] = mstat[i * 128 + lane];
      lB[i] = mstat[i * 128 + 64 + lane];
      mS = fmaxf(mS, mB[i]);
    }
    float f0 = exp2f(m_run - mS);
    float fi[3];
    float l_tot = l_run * f0;
#pragma unroll
    for (int i = 0; i < 3; ++i) { fi[i] = exp2f(mB[i] - mS); l_tot += lB[i] * fi[i]; }
    float inv = 1.0f / l_tot;
#pragma unroll
    for (int mt = 0; mt < 2; ++mt) {
#pragma unroll
      for (int rgq = 0; rgq < 4; ++rgq) {
        s16x4 pb;
#pragma unroll
        for (int e = 0; e < 4; ++e) {
          int rg = 4 * rgq + e;
          float val = o[mt][rg] * f0;
#pragma unroll
          for (int i = 0; i < 3; ++i)
            val += obuf[i * 2048 + (mt * 16 + rg) * 64 + lane] * fi[i];
          pb[e] = (short)f2bf(val * inv);
        }
        int d0 = 32 * mt + 8 * rgq + 4 * h;
        int byte = qcol * 128 + d0 * 2;
        *(s16x4*)((char*)clds + (byte ^ swzK(qcol))) = pb;
      }
    }
  }
  __syncthreads();

  // ---- fused output projection: out[q0..q0+32) x 1024 = ctx(32x64) . Wo^T ----
  s16x8 afr[2][2];
#pragma unroll
  for (int mt = 0; mt < 2; ++mt)
#pragma unroll
    for (int kk = 0; kk < 2; ++kk) {
      int ra = 16 * mt + c;
      afr[mt][kk] = *(const s16x8*)((char*)clds +
                      ((ra * 128 + (32 * kk + 8 * g) * 2) ^ swzK(ra)));
    }
  const int wchunk = (lane & 15) * 32 + (lane >> 4) * 8;   // Wo_b frag lane offset
  const size_t orow0 = (size_t)(b * TT + q0);
#pragma unroll 4
  for (int nt = 0; nt < 16; ++nt) {
    int col = wv * 256 + 16 * nt + c;
    s16x8 bfr[2];
#pragma unroll
    for (int kk = 0; kk < 2; ++kk)
      bfr[kk] = *(const s16x8*)(Wo_b + (size_t)(wv * 16 + nt) * 1024
                                + kk * 512 + wchunk);
    f32x4 acc4[2];
#pragma unroll
    for (int mt = 0; mt < 2; ++mt)
#pragma unroll
      for (int e = 0; e < 4; ++e) acc4[mt][e] = 0.0f;
#pragma unroll
    for (int kk = 0; kk < 2; ++kk)
#pragma unroll
      for (int mt = 0; mt < 2; ++mt)
        acc4[mt] = __builtin_amdgcn_mfma_f32_16x16x32_bf16(afr[mt][kk], bfr[kk],
                                                           acc4[mt], 0, 0, 0);
    float bias = bo[col];
#pragma unroll
    for (int mt = 0; mt < 2; ++mt)
#pragma unroll
      for (int i = 0; i < 4; ++i) {
        size_t row = orow0 + 16 * mt + 4 * g + i;
        out[row * HH + col] = acc4[mt][i] + bias;
      }
  }
}

// ---------------------------------------------------------------------------
extern "C" void kernel_launch(void* const* d_in, const int* in_sizes, int n_in,
                              void* d_out, int out_size, void* d_ws, size_t ws_size,
                              hipStream_t stream)
{
  const float* y  = (const float*)d_in[0];
  const float* Wq = (const float*)d_in[1];
  const float* bq = (const float*)d_in[2];
  const float* Wk = (const float*)d_in[3];
  const float* bk = (const float*)d_in[4];
  const float* Wv = (const float*)d_in[5];
  const float* bv = (const float*)d_in[6];
  const float* Wo = (const float*)d_in[7];
  const float* bo = (const float*)d_in[8];
  float* out = (float*)d_out;
  char* ws = (char*)d_ws;
  // workspace layout (bytes) — total 6,815,744 (6.5 MiB)
  unsigned short* Wall  = (unsigned short*)(ws);                        // 384 KiB
  unsigned short* Wo_b  = (unsigned short*)(ws + 393216);               // 128 KiB
  unsigned short* q_ws  = (unsigned short*)(ws + 524288);               // 2 MiB
  unsigned short* k_ws  = (unsigned short*)(ws + 524288 + 2097152);     // 2 MiB
  unsigned short* vT_ws = (unsigned short*)(ws + 524288 + 2 * 2097152); // 2 MiB

  prep_kernel<<<dim3(256), dim3(256), 0, stream>>>(Wq, Wk, Wv, Wo, Wall, Wo_b);
  qkv_kernel<<<dim3(512), dim3(256), 0, stream>>>(y, Wall, bq, bk, bv, q_ws, k_ws, vT_ws);
  attn_kernel<<<dim3(512), dim3(256), 0, stream>>>(q_ws, k_ws, vT_ws, Wo_b, bo, out);
}

// Round 16
// 57.257 us; speedup vs baseline: 1.4127x; 1.0153x over previous
//
#include <hip/hip_runtime.h>

// ---------------------------------------------------------------------------
// Causal self-attention, B=4 T=4096 H=1024 D=64, fp32 in/out, bf16 MFMA inside.
// prep (weights->bf16) -> qkv GEMM -> fused flash attn + out-proj.
// attn (R11 structure + 2 chain-shortening changes):
//   grid 512 = 4b x 128 q-tiles(32 rows), complementary pairing; 256 thr =
//   4 waves = 4-way KV parity; __launch_bounds__(256,2).
//   (1) K double-buffer prefetch: tile kt issues kt+4's K loads post-QK.
//   (2) OFF-PATH softmax: exp2 uses stale per-row reference m_used right
//       after mask (no tree-max/shfl on the critical path); max check runs
//       AFTER PV on exp'd P (monotonic): if max(P) > 2^8, rescale o,l by
//       1/maxP and m_used += log2(maxP).  First tile establishes m_used.
// P^T in-register via v_cvt_pk_bf16_f32 + v_permlane32_swap_b32.
// Fragment-native layouts for q/k/vT/Wo_b (all frag loads = 1KB wave-loads).
// ws usage: 6.5 MiB (Wall 384K | Wo_b 128K | q 2M | k 2M | vT 2M).
//
// Layouts (elements, per batch b):
//   q/k (t, d):  b*T*D + (t>>5)*2048 + (d>>4)*512 + (t&31)*16 + (d&15)
//   vT  (d, t):  b*D*T + (t>>6)*4096 + (d>>5)*2048 + ((t>>4)&3)*512
//                + (d&31)*16 + (t&15)
//   Wo_b(hcol,d): (hcol>>4)*1024 + (d>>5)*512 + (hcol&15)*32 + ((d>>3)&3)*8 + (d&7)
// ---------------------------------------------------------------------------

typedef __attribute__((ext_vector_type(4)))  float f32x4;
typedef __attribute__((ext_vector_type(16))) float f32x16;
typedef __attribute__((ext_vector_type(8)))  short s16x8;
typedef __attribute__((ext_vector_type(4)))  short s16x4;

#define DEV static __device__ __forceinline__

static constexpr int TT = 4096;        // sequence length
static constexpr int HH = 1024;        // hidden
static constexpr int DD = 64;          // head dim
static constexpr float MNEG = -3.0e38f; // finite -inf substitute (NaN-proof)

DEV unsigned short f2bf(float f) {     // round-to-nearest-even fp32->bf16
  union { float f; unsigned int u; } v; v.f = f;
  unsigned int r = v.u + 0x7FFFu + ((v.u >> 16) & 1u);
  return (unsigned short)(r >> 16);
}

DEV unsigned int cvtpk(float lo, float hi) {   // 2 bf16 in one u32 (HW RNE)
  unsigned int r;
  asm("v_cvt_pk_bf16_f32 %0, %1, %2" : "=v"(r) : "v"(lo), "v"(hi));
  return r;
}

DEV s16x8 mk8(unsigned int w0, unsigned int w1, unsigned int w2, unsigned int w3) {
  union { unsigned int u[4]; s16x8 v; } c;
  c.u[0] = w0; c.u[1] = w1; c.u[2] = w2; c.u[3] = w3; return c.v;
}

// XOR swizzles for 128B-row LDS tiles (bank-conflict avoidance)
DEV int swzA(int row) { return ((row & 7) << 4); }                     // 16-row tiles
DEV int swzK(int row) { return ((row & 7) << 4) ^ ((row & 8) << 3); }  // 32-row tiles

// ---------------------------------------------------------------------------
// Kernel 0: weights fp32 -> bf16.  Wall rows: [0,64)=Wq [64,128)=Wk [128,192)=Wv
// Wo_b written in proj-fragment layout.
// ---------------------------------------------------------------------------
__global__ void prep_kernel(const float* __restrict__ Wq, const float* __restrict__ Wk,
                            const float* __restrict__ Wv, const float* __restrict__ Wo,
                            unsigned short* __restrict__ Wall,
                            unsigned short* __restrict__ Wo_b)
{
  int i = blockIdx.x * blockDim.x + threadIdx.x;
  int stride = gridDim.x * blockDim.x;
  const int n1 = 64 * HH;
  for (int idx = i; idx < 3 * n1; idx += stride) {
    float v = idx < n1 ? Wq[idx] : (idx < 2 * n1 ? Wk[idx - n1] : Wv[idx - 2 * n1]);
    Wall[idx] = f2bf(v);
  }
  for (int idx = i; idx < HH * DD; idx += stride) {
    int hcol = idx >> 6, d = idx & 63;
    size_t off = (size_t)(hcol >> 4) * 1024 + (d >> 5) * 512 + (hcol & 15) * 32
               + ((d >> 3) & 3) * 8 + (d & 7);
    Wo_b[off] = f2bf(Wo[idx]);
  }
}

// ---------------------------------------------------------------------------
// Kernel 1: QKV projection.  512 blocks x 256 thr (2 blocks/CU); block = 32
// rows x 192 cols; K=1024 in 16 steps of 64.  Epilogue: acc -> LDS transpose
// -> contiguous 16B stores into fragment-native layouts.  q scaled log2e/8.
// ---------------------------------------------------------------------------
__global__ __launch_bounds__(256, 2) void qkv_kernel(
    const float* __restrict__ y, const unsigned short* __restrict__ Wall,
    const float* __restrict__ bq, const float* __restrict__ bk,
    const float* __restrict__ bv,
    unsigned short* __restrict__ q_ws, unsigned short* __restrict__ k_ws,
    unsigned short* __restrict__ vT_ws)
{
  __shared__ unsigned short ylds[2][32 * 64];
  __shared__ unsigned short wlds[2][192 * 64];
  const int t = threadIdx.x;
  const int wv = t >> 6, lane = t & 63, g = lane >> 4, c = lane & 15;
  const int row0 = blockIdx.x * 32;
  const int bb = row0 >> 12;
  const int tb = row0 & 4095;                  // 32-aligned
  const int yrow = t >> 3, ycol0 = (t & 7) * 8;

  f32x4 acc[2][3];
#pragma unroll
  for (int m = 0; m < 2; ++m)
#pragma unroll
    for (int i = 0; i < 3; ++i)
#pragma unroll
      for (int e = 0; e < 4; ++e) acc[m][i][e] = 0.0f;

  f32x4 yr[2];
  s16x8 wr[6];

  auto load_tiles = [&](int kb) {
    const float* src = y + (size_t)(row0 + yrow) * HH + kb * 64 + ycol0;
    yr[0] = *(const f32x4*)(src);
    yr[1] = *(const f32x4*)(src + 4);
#pragma unroll
    for (int ii = 0; ii < 6; ++ii) {
      int ch = t + ii * 256;
      int rw = ch >> 3, c0 = (ch & 7) * 8;
      wr[ii] = *(const s16x8*)(Wall + (size_t)rw * HH + kb * 64 + c0);
    }
  };
  auto write_tiles = [&](int buf) {
    s16x8 h0;
#pragma unroll
    for (int e = 0; e < 4; ++e) {
      h0[e]     = (short)f2bf(yr[0][e]);
      h0[e + 4] = (short)f2bf(yr[1][e]);
    }
    int byte0 = yrow * 128 + ycol0 * 2;
    *(s16x8*)((char*)ylds[buf] + (byte0 ^ swzA(yrow))) = h0;
#pragma unroll
    for (int ii = 0; ii < 6; ++ii) {
      int ch = t + ii * 256;
      int rw = ch >> 3, c0 = (ch & 7) * 8;
      int byte = rw * 128 + c0 * 2;
      *(s16x8*)((char*)wlds[buf] + (byte ^ swzA(rw))) = wr[ii];
    }
  };

  load_tiles(0);
  write_tiles(0);
  __syncthreads();
  for (int kb = 0; kb < 16; ++kb) {
    int buf = kb & 1;
    if (kb < 15) load_tiles(kb + 1);
#pragma unroll
    for (int kk = 0; kk < 2; ++kk) {
      s16x8 a[2], bfr[3];
#pragma unroll
      for (int m = 0; m < 2; ++m) {
        int ra = 16 * m + c;
        a[m] = *(const s16x8*)((char*)ylds[buf] +
                 ((ra * 128 + (kk * 32 + 8 * g) * 2) ^ swzA(ra)));
      }
#pragma unroll
      for (int i = 0; i < 3; ++i) {
        int rb = 16 * (3 * wv + i) + c;
        bfr[i] = *(const s16x8*)((char*)wlds[buf] +
                   ((rb * 128 + (kk * 32 + 8 * g) * 2) ^ swzA(rb)));
      }
#pragma unroll
      for (int m = 0; m < 2; ++m)
#pragma unroll
        for (int i = 0; i < 3; ++i)
          acc[m][i] = __builtin_amdgcn_mfma_f32_16x16x32_bf16(a[m], bfr[i], acc[m][i], 0, 0, 0);
    }
    __syncthreads();
    if (kb < 15) { write_tiles((kb + 1) & 1); __syncthreads(); }
  }

  // ---- epilogue: bias (+q scale) -> LDS [q 32x64, k 32x64, vT 64x32] ----
  unsigned short* elds = &wlds[0][0];     // 12,288 B alias (wlds dead)
  const float qsc = 1.4426950408889634f / 8.0f;   // log2e / sqrt(Dk)
#pragma unroll
  for (int m = 0; m < 2; ++m)
#pragma unroll
    for (int i = 0; i < 3; ++i) {
      int nt = 3 * wv + i;
      int sec = nt >> 2;
      int dcol = (nt & 3) * 16 + c;
      float bias = sec == 0 ? bq[dcol] : (sec == 1 ? bk[dcol] : bv[dcol]);
#pragma unroll
      for (int i2 = 0; i2 < 4; ++i2) {
        int rl = 16 * m + 4 * g + i2;
        float val = acc[m][i][i2] + bias;
        if (sec == 0) val *= qsc;
        if (sec < 2) elds[sec * 2048 + rl * 64 + dcol] = f2bf(val);
        else         elds[4096 + dcol * 32 + rl]       = f2bf(val);
      }
    }
  __syncthreads();
  // ---- contiguous 16B stores into fragment-native global layouts ----
  {
    int trow = t >> 3, d0 = (t & 7) * 8;           // q,k assignment
    s16x8 vq = *(const s16x8*)(elds + trow * 64 + d0);
    s16x8 vk = *(const s16x8*)(elds + 2048 + trow * 64 + d0);
    size_t offqk = (size_t)bb * (TT * DD) + (size_t)(tb >> 5) * 2048
                 + (d0 >> 4) * 512 + trow * 16 + (d0 & 15);
    *(s16x8*)(q_ws + offqk) = vq;
    *(s16x8*)(k_ws + offqk) = vk;
    int d = t >> 2, tq = (t & 3) * 8;              // v assignment
    s16x8 vvv = *(const s16x8*)(elds + 4096 + d * 32 + tq);
    int tg = tb + tq;
    size_t offv = (size_t)bb * (DD * TT) + (size_t)(tg >> 6) * 4096
                + (d >> 5) * 2048 + ((tg >> 4) & 3) * 512 + (d & 31) * 16 + (tg & 15);
    *(s16x8*)(vT_ws + offv) = vvv;
  }
}

// ---------------------------------------------------------------------------
// Kernel 2: fused flash attention + output projection.
// Grid 512 = 4 b x 128 q-tiles(32 rows); complementary pairing j32(s).
// 4 waves = 4-way KV parity.  K-prefetch double buffer + off-path softmax.
// ---------------------------------------------------------------------------
__global__ __launch_bounds__(256, 2) void attn_kernel(
    const unsigned short* __restrict__ q_ws, const unsigned short* __restrict__ k_ws,
    const unsigned short* __restrict__ vT_ws, const unsigned short* __restrict__ Wo_b,
    const float* __restrict__ bo, float* __restrict__ out)
{
  __shared__ float obuf[3 * 2048];          // waves 1-3 O^T          (24 KB)
  __shared__ float mstat[3 * 128];          // waves 1-3 m,l          (1.5 KB)
  __shared__ unsigned short clds[32 * 64];  // merged ctx bf16 [q][d] (4 KB)
  const int t = threadIdx.x, wv = t >> 6, lane = t & 63;
  const int qcol = lane & 31, h = lane >> 5;
  const int b = blockIdx.x & 3;
  const int jslot = blockIdx.x >> 2;
  const int j32 = (jslot < 64) ? (2 * jslot) : (127 - 2 * (jslot - 64));
  const int q0 = j32 * 32;
  const int L = j32 >> 1;                   // last KV tile (diagonal)
  const size_t base  = (size_t)b * TT * DD; // q,k frag space
  const size_t vbase = (size_t)b * DD * TT; // vT frag space
  const int g = lane >> 4, c = lane & 15;   // proj phase
  const int lchunk = (lane & 31) * 16 + (lane >> 5) * 8;   // frag lane offset

  // Q B-frags (contiguous 1KB per kk)
  s16x8 qf[4];
  {
    const unsigned short* qp = q_ws + base + (size_t)j32 * 2048;
#pragma unroll
    for (int kk = 0; kk < 4; ++kk) qf[kk] = *(const s16x8*)(qp + kk * 512 + lchunk);
  }
  f32x16 o[2];
#pragma unroll
  for (int mt = 0; mt < 2; ++mt)
#pragma unroll
    for (int rg = 0; rg < 16; ++rg) o[mt][rg] = 0.0f;
  float m_used = MNEG, l_run = 0.0f;
  bool first = true;

  auto loadK = [&](int kt, s16x8 (&kf)[2][4]) {
#pragma unroll
    for (int mt = 0; mt < 2; ++mt)
#pragma unroll
      for (int kk = 0; kk < 4; ++kk)
        kf[mt][kk] = *(const s16x8*)(k_ws + base +
                       (size_t)(2 * kt + mt) * 2048 + kk * 512 + lchunk);
  };

  auto tile = [&](int kt, s16x8 (&kf)[2][4], s16x8 (&kfn)[2][4]) {
    const int kv0 = kt * 64;
    // ---- S^T = K . Q^T ----
    f32x16 s[2];
#pragma unroll
    for (int mt = 0; mt < 2; ++mt)
#pragma unroll
      for (int rg = 0; rg < 16; ++rg) s[mt][rg] = 0.0f;
    __builtin_amdgcn_s_setprio(1);
#pragma unroll
    for (int kk = 0; kk < 4; ++kk)
#pragma unroll
      for (int mt = 0; mt < 2; ++mt)
        s[mt] = __builtin_amdgcn_mfma_f32_32x32x16_bf16(kf[mt][kk], qf[kk], s[mt], 0, 0, 0);
    __builtin_amdgcn_s_setprio(0);
    // ---- PREFETCH next parity tile's K (latency hidden under this tile) ----
    if (kt + 4 <= L) loadK(kt + 4, kfn);
    // ---- V^T A-frags (issued early; consumed at PV) ----
    s16x8 vf[2][4];
#pragma unroll
    for (int mt = 0; mt < 2; ++mt)
#pragma unroll
      for (int ks = 0; ks < 4; ++ks)
        vf[mt][ks] = *(const s16x8*)(vT_ws + vbase +
                       (size_t)kt * 4096 + mt * 2048 + ks * 512 + lchunk);
    // ---- causal mask (diagonal tile only) ----
    if (kt == L) {
      int qq = q0 + qcol;
#pragma unroll
      for (int mt = 0; mt < 2; ++mt)
#pragma unroll
        for (int rg = 0; rg < 16; ++rg) {
          int kvabs = kv0 + 32 * mt + (rg & 3) + 8 * (rg >> 2) + 4 * h;
          if (kvabs > qq) s[mt][rg] = MNEG;
        }
    }
    // ---- first tile: establish per-row reference exactly (one-time chain) ----
    if (first) {
      first = false;
      float mx[16];
#pragma unroll
      for (int e = 0; e < 16; ++e) mx[e] = fmaxf(s[0][e], s[1][e]);
#pragma unroll
      for (int st = 8; st >= 1; st >>= 1)
#pragma unroll
        for (int e = 0; e < 8; ++e) if (e < st) mx[e] = fmaxf(mx[e], mx[e + st]);
      m_used = fmaxf(mx[0], __shfl_xor(mx[0], 32));
    }
    // ---- OFF-PATH softmax: exp with (possibly stale) m_used, no pre-max ----
#pragma unroll
    for (int mt = 0; mt < 2; ++mt)
#pragma unroll
      for (int rg = 0; rg < 16; ++rg) s[mt][rg] = exp2f(s[mt][rg] - m_used);
    // ---- pack P^T B-frags: cvt_pk pairs + permlane32_swap (T12) ----
    s16x8 pf[4];
#pragma unroll
    for (int mt = 0; mt < 2; ++mt) {
      unsigned int a0 = cvtpk(s[mt][0],  s[mt][1]);
      unsigned int a1 = cvtpk(s[mt][2],  s[mt][3]);
      unsigned int b0 = cvtpk(s[mt][4],  s[mt][5]);
      unsigned int b1 = cvtpk(s[mt][6],  s[mt][7]);
      unsigned int c0 = cvtpk(s[mt][8],  s[mt][9]);
      unsigned int c1 = cvtpk(s[mt][10], s[mt][11]);
      unsigned int d0 = cvtpk(s[mt][12], s[mt][13]);
      unsigned int d1 = cvtpk(s[mt][14], s[mt][15]);
      asm("v_permlane32_swap_b32 %0, %1" : "+v"(a0), "+v"(b0));
      asm("v_permlane32_swap_b32 %0, %1" : "+v"(a1), "+v"(b1));
      asm("v_permlane32_swap_b32 %0, %1" : "+v"(c0), "+v"(d0));
      asm("v_permlane32_swap_b32 %0, %1" : "+v"(c1), "+v"(d1));
      pf[2 * mt]     = mk8(a0, a1, b0, b1);
      pf[2 * mt + 1] = mk8(c0, c1, d0, d1);
    }
    // ---- O^T += V^T . P^T ----
    __builtin_amdgcn_s_setprio(1);
#pragma unroll
    for (int ks = 0; ks < 4; ++ks)
#pragma unroll
      for (int mt = 0; mt < 2; ++mt)
        o[mt] = __builtin_amdgcn_mfma_f32_32x32x16_bf16(vf[mt][ks], pf[ks], o[mt], 0, 0, 0);
    __builtin_amdgcn_s_setprio(0);
    // ---- off-path stats on exp'd P (monotonic => max check valid) ----
    float sm[16], mxp[16];
#pragma unroll
    for (int e = 0; e < 16; ++e) {
      sm[e]  = s[0][e] + s[1][e];
      mxp[e] = fmaxf(s[0][e], s[1][e]);
    }
#pragma unroll
    for (int st = 8; st >= 1; st >>= 1)
#pragma unroll
      for (int e = 0; e < 8; ++e)
        if (e < st) { sm[e] += sm[e + st]; mxp[e] = fmaxf(mxp[e], mxp[e + st]); }
    float rowsum = sm[0] + __shfl_xor(sm[0], 32);     // full-row sum
    float mp = fmaxf(mxp[0], __shfl_xor(mxp[0], 32)); // full-row max(P)
    l_run += rowsum;
    if (!__all(mp <= 256.0f)) {          // rare: reference drifted > 2^8
      float mpc = fmaxf(mp, 1.0f);       // only shrink rows that grew
      float dlt = log2f(mpc);
      float alpha = 1.0f / mpc;
      m_used += dlt;
      l_run *= alpha;
#pragma unroll
      for (int mt = 0; mt < 2; ++mt)
#pragma unroll
        for (int rg = 0; rg < 16; ++rg) o[mt][rg] *= alpha;
    }
  };

  // ---- pipelined KV loop (named double buffers; no runtime indexing) ----
  s16x8 kfA[2][4], kfB[2][4];
  int kt = wv;
  if (kt <= L) loadK(kt, kfA);
  while (kt <= L) {
    tile(kt, kfA, kfB);
    kt += 4;
    if (kt > L) break;
    tile(kt, kfB, kfA);
    kt += 4;
  }

  // ---- 4-way flash merge (wave 0 combines), ctx -> LDS bf16 [q][d] ----
  if (wv != 0) {
#pragma unroll
    for (int mt = 0; mt < 2; ++mt)
#pragma unroll
      for (int rg = 0; rg < 16; ++rg)
        obuf[(wv - 1) * 2048 + (mt * 16 + rg) * 64 + lane] = o[mt][rg];
    mstat[(wv - 1) * 128 + lane] = m_used;
    mstat[(wv - 1) * 128 + 64 + lane] = l_run;
  }
  __syncthreads();
  if (wv == 0) {
    float mB[3], lB[3];
    float mS = m_used;
#pragma unroll
    for (int i = 0; i < 3; ++i) {
      mB[i] = mstat[i * 128 + lane];
      lB[i] = mstat[i * 128 + 64 + lane];
      mS = fmaxf(mS, mB[i]);
    }
    float f0 = exp2f(m_used - mS);
    float fi[3];
    float l_tot = l_run * f0;
#pragma unroll
    for (int i = 0; i < 3; ++i) { fi[i] = exp2f(mB[i] - mS); l_tot += lB[i] * fi[i]; }
    float inv = 1.0f / l_tot;
#pragma unroll
    for (int mt = 0; mt < 2; ++mt) {
#pragma unroll
      for (int rgq = 0; rgq < 4; ++rgq) {
        s16x4 pb;
#pragma unroll
        for (int e = 0; e < 4; ++e) {
          int rg = 4 * rgq + e;
          float val = o[mt][rg] * f0;
#pragma unroll
          for (int i = 0; i < 3; ++i)
            val += obuf[i * 2048 + (mt * 16 + rg) * 64 + lane] * fi[i];
          pb[e] = (short)f2bf(val * inv);
        }
        int d0 = 32 * mt + 8 * rgq + 4 * h;
        int byte = qcol * 128 + d0 * 2;
        *(s16x4*)((char*)clds + (byte ^ swzK(qcol))) = pb;
      }
    }
  }
  __syncthreads();

  // ---- fused output projection: out[q0..q0+32) x 1024 = ctx(32x64) . Wo^T ----
  s16x8 afr[2][2];
#pragma unroll
  for (int mt = 0; mt < 2; ++mt)
#pragma unroll
    for (int kk = 0; kk < 2; ++kk) {
      int ra = 16 * mt + c;
      afr[mt][kk] = *(const s16x8*)((char*)clds +
                      ((ra * 128 + (32 * kk + 8 * g) * 2) ^ swzK(ra)));
    }
  const int wchunk = (lane & 15) * 32 + (lane >> 4) * 8;   // Wo_b frag lane offset
  const size_t orow0 = (size_t)(b * TT + q0);
#pragma unroll 4
  for (int nt = 0; nt < 16; ++nt) {
    int col = wv * 256 + 16 * nt + c;
    s16x8 bfr[2];
#pragma unroll
    for (int kk = 0; kk < 2; ++kk)
      bfr[kk] = *(const s16x8*)(Wo_b + (size_t)(wv * 16 + nt) * 1024
                                + kk * 512 + wchunk);
    f32x4 acc4[2];
#pragma unroll
    for (int mt = 0; mt < 2; ++mt)
#pragma unroll
      for (int e = 0; e < 4; ++e) acc4[mt][e] = 0.0f;
#pragma unroll
    for (int kk = 0; kk < 2; ++kk)
#pragma unroll
      for (int mt = 0; mt < 2; ++mt)
        acc4[mt] = __builtin_amdgcn_mfma_f32_16x16x32_bf16(afr[mt][kk], bfr[kk],
                                                           acc4[mt], 0, 0, 0);
    float bias = bo[col];
#pragma unroll
    for (int mt = 0; mt < 2; ++mt)
#pragma unroll
      for (int i = 0; i < 4; ++i) {
        size_t row = orow0 + 16 * mt + 4 * g + i;
        out[row * HH + col] = acc4[mt][i] + bias;
      }
  }
}

// ---------------------------------------------------------------------------
extern "C" void kernel_launch(void* const* d_in, const int* in_sizes, int n_in,
                              void* d_out, int out_size, void* d_ws, size_t ws_size,
                              hipStream_t stream)
{
  const float* y  = (const float*)d_in[0];
  const float* Wq = (const float*)d_in[1];
  const float* bq = (const float*)d_in[2];
  const float* Wk = (const float*)d_in[3];
  const float* bk = (const float*)d_in[4];
  const float* Wv = (const float*)d_in[5];
  const float* bv = (const float*)d_in[6];
  const float* Wo = (const float*)d_in[7];
  const float* bo = (const float*)d_in[8];
  float* out = (float*)d_out;
  char* ws = (char*)d_ws;
  // workspace layout (bytes) — total 6,815,744 (6.5 MiB)
  unsigned short* Wall  = (unsigned short*)(ws);                        // 384 KiB
  unsigned short* Wo_b  = (unsigned short*)(ws + 393216);               // 128 KiB
  unsigned short* q_ws  = (unsigned short*)(ws + 524288);               // 2 MiB
  unsigned short* k_ws  = (unsigned short*)(ws + 524288 + 2097152);     // 2 MiB
  unsigned short* vT_ws = (unsigned short*)(ws + 524288 + 2 * 2097152); // 2 MiB

  prep_kernel<<<dim3(256), dim3(256), 0, stream>>>(Wq, Wk, Wv, Wo, Wall, Wo_b);
  qkv_kernel<<<dim3(512), dim3(256), 0, stream>>>(y, Wall, bq, bk, bv, q_ws, k_ws, vT_ws);
  attn_kernel<<<dim3(512), dim3(256), 0, stream>>>(q_ws, k_ws, vT_ws, Wo_b, bo, out);
}

// Round 17
// 57.066 us; speedup vs baseline: 1.4174x; 1.0034x over previous
//
#include <hip/hip_runtime.h>

// ---------------------------------------------------------------------------
// Causal self-attention, B=4 T=4096 H=1024 D=64, fp32 in/out, bf16 MFMA inside.
// prep (weights->bf16) -> qkv GEMM -> fused flash attn + out-proj.
// attn (R16 base + register-liveness cuts so V loads can hoist):
//   grid 512 = 4b x 128 q-tiles(32 rows), complementary pairing; 256 thr =
//   4 waves = 4-way KV parity; __launch_bounds__(256,2).
//   K double-buffer prefetch; OFF-PATH softmax (stale per-row reference
//   m_used, post-hoc rescale if max(P) > 2^8); per-mt exp+pack (s[mt] dies
//   at pack); per-mt inline row stats (2 scalars, not 32-reg arrays).
// P^T in-register via v_cvt_pk_bf16_f32 + v_permlane32_swap_b32.
// Fragment-native layouts for q/k/vT/Wo_b (all frag loads = 1KB wave-loads).
// ws usage: 6.5 MiB (Wall 384K | Wo_b 128K | q 2M | k 2M | vT 2M).
//
// Layouts (elements, per batch b):
//   q/k (t, d):  b*T*D + (t>>5)*2048 + (d>>4)*512 + (t&31)*16 + (d&15)
//   vT  (d, t):  b*D*T + (t>>6)*4096 + (d>>5)*2048 + ((t>>4)&3)*512
//                + (d&31)*16 + (t&15)
//   Wo_b(hcol,d): (hcol>>4)*1024 + (d>>5)*512 + (hcol&15)*32 + ((d>>3)&3)*8 + (d&7)
// ---------------------------------------------------------------------------

typedef __attribute__((ext_vector_type(4)))  float f32x4;
typedef __attribute__((ext_vector_type(16))) float f32x16;
typedef __attribute__((ext_vector_type(8)))  short s16x8;
typedef __attribute__((ext_vector_type(4)))  short s16x4;

#define DEV static __device__ __forceinline__

static constexpr int TT = 4096;        // sequence length
static constexpr int HH = 1024;        // hidden
static constexpr int DD = 64;          // head dim
static constexpr float MNEG = -3.0e38f; // finite -inf substitute (NaN-proof)

DEV unsigned short f2bf(float f) {     // round-to-nearest-even fp32->bf16
  union { float f; unsigned int u; } v; v.f = f;
  unsigned int r = v.u + 0x7FFFu + ((v.u >> 16) & 1u);
  return (unsigned short)(r >> 16);
}

DEV unsigned int cvtpk(float lo, float hi) {   // 2 bf16 in one u32 (HW RNE)
  unsigned int r;
  asm("v_cvt_pk_bf16_f32 %0, %1, %2" : "=v"(r) : "v"(lo), "v"(hi));
  return r;
}

DEV s16x8 mk8(unsigned int w0, unsigned int w1, unsigned int w2, unsigned int w3) {
  union { unsigned int u[4]; s16x8 v; } c;
  c.u[0] = w0; c.u[1] = w1; c.u[2] = w2; c.u[3] = w3; return c.v;
}

// XOR swizzles for 128B-row LDS tiles (bank-conflict avoidance)
DEV int swzA(int row) { return ((row & 7) << 4); }                     // 16-row tiles
DEV int swzK(int row) { return ((row & 7) << 4) ^ ((row & 8) << 3); }  // 32-row tiles

// ---------------------------------------------------------------------------
// Kernel 0: weights fp32 -> bf16.  Wall rows: [0,64)=Wq [64,128)=Wk [128,192)=Wv
// Wo_b written in proj-fragment layout.
// ---------------------------------------------------------------------------
__global__ void prep_kernel(const float* __restrict__ Wq, const float* __restrict__ Wk,
                            const float* __restrict__ Wv, const float* __restrict__ Wo,
                            unsigned short* __restrict__ Wall,
                            unsigned short* __restrict__ Wo_b)
{
  int i = blockIdx.x * blockDim.x + threadIdx.x;
  int stride = gridDim.x * blockDim.x;
  const int n1 = 64 * HH;
  for (int idx = i; idx < 3 * n1; idx += stride) {
    float v = idx < n1 ? Wq[idx] : (idx < 2 * n1 ? Wk[idx - n1] : Wv[idx - 2 * n1]);
    Wall[idx] = f2bf(v);
  }
  for (int idx = i; idx < HH * DD; idx += stride) {
    int hcol = idx >> 6, d = idx & 63;
    size_t off = (size_t)(hcol >> 4) * 1024 + (d >> 5) * 512 + (hcol & 15) * 32
               + ((d >> 3) & 3) * 8 + (d & 7);
    Wo_b[off] = f2bf(Wo[idx]);
  }
}

// ---------------------------------------------------------------------------
// Kernel 1: QKV projection.  512 blocks x 256 thr (2 blocks/CU); block = 32
// rows x 192 cols; K=1024 in 16 steps of 64.  Epilogue: acc -> LDS transpose
// -> contiguous 16B stores into fragment-native layouts.  q scaled log2e/8.
// ---------------------------------------------------------------------------
__global__ __launch_bounds__(256, 2) void qkv_kernel(
    const float* __restrict__ y, const unsigned short* __restrict__ Wall,
    const float* __restrict__ bq, const float* __restrict__ bk,
    const float* __restrict__ bv,
    unsigned short* __restrict__ q_ws, unsigned short* __restrict__ k_ws,
    unsigned short* __restrict__ vT_ws)
{
  __shared__ unsigned short ylds[2][32 * 64];
  __shared__ unsigned short wlds[2][192 * 64];
  const int t = threadIdx.x;
  const int wv = t >> 6, lane = t & 63, g = lane >> 4, c = lane & 15;
  const int row0 = blockIdx.x * 32;
  const int bb = row0 >> 12;
  const int tb = row0 & 4095;                  // 32-aligned
  const int yrow = t >> 3, ycol0 = (t & 7) * 8;

  f32x4 acc[2][3];
#pragma unroll
  for (int m = 0; m < 2; ++m)
#pragma unroll
    for (int i = 0; i < 3; ++i)
#pragma unroll
      for (int e = 0; e < 4; ++e) acc[m][i][e] = 0.0f;

  f32x4 yr[2];
  s16x8 wr[6];

  auto load_tiles = [&](int kb) {
    const float* src = y + (size_t)(row0 + yrow) * HH + kb * 64 + ycol0;
    yr[0] = *(const f32x4*)(src);
    yr[1] = *(const f32x4*)(src + 4);
#pragma unroll
    for (int ii = 0; ii < 6; ++ii) {
      int ch = t + ii * 256;
      int rw = ch >> 3, c0 = (ch & 7) * 8;
      wr[ii] = *(const s16x8*)(Wall + (size_t)rw * HH + kb * 64 + c0);
    }
  };
  auto write_tiles = [&](int buf) {
    s16x8 h0;
#pragma unroll
    for (int e = 0; e < 4; ++e) {
      h0[e]     = (short)f2bf(yr[0][e]);
      h0[e + 4] = (short)f2bf(yr[1][e]);
    }
    int byte0 = yrow * 128 + ycol0 * 2;
    *(s16x8*)((char*)ylds[buf] + (byte0 ^ swzA(yrow))) = h0;
#pragma unroll
    for (int ii = 0; ii < 6; ++ii) {
      int ch = t + ii * 256;
      int rw = ch >> 3, c0 = (ch & 7) * 8;
      int byte = rw * 128 + c0 * 2;
      *(s16x8*)((char*)wlds[buf] + (byte ^ swzA(rw))) = wr[ii];
    }
  };

  load_tiles(0);
  write_tiles(0);
  __syncthreads();
  for (int kb = 0; kb < 16; ++kb) {
    int buf = kb & 1;
    if (kb < 15) load_tiles(kb + 1);
#pragma unroll
    for (int kk = 0; kk < 2; ++kk) {
      s16x8 a[2], bfr[3];
#pragma unroll
      for (int m = 0; m < 2; ++m) {
        int ra = 16 * m + c;
        a[m] = *(const s16x8*)((char*)ylds[buf] +
                 ((ra * 128 + (kk * 32 + 8 * g) * 2) ^ swzA(ra)));
      }
#pragma unroll
      for (int i = 0; i < 3; ++i) {
        int rb = 16 * (3 * wv + i) + c;
        bfr[i] = *(const s16x8*)((char*)wlds[buf] +
                   ((rb * 128 + (kk * 32 + 8 * g) * 2) ^ swzA(rb)));
      }
#pragma unroll
      for (int m = 0; m < 2; ++m)
#pragma unroll
        for (int i = 0; i < 3; ++i)
          acc[m][i] = __builtin_amdgcn_mfma_f32_16x16x32_bf16(a[m], bfr[i], acc[m][i], 0, 0, 0);
    }
    __syncthreads();
    if (kb < 15) { write_tiles((kb + 1) & 1); __syncthreads(); }
  }

  // ---- epilogue: bias (+q scale) -> LDS [q 32x64, k 32x64, vT 64x32] ----
  unsigned short* elds = &wlds[0][0];     // 12,288 B alias (wlds dead)
  const float qsc = 1.4426950408889634f / 8.0f;   // log2e / sqrt(Dk)
#pragma unroll
  for (int m = 0; m < 2; ++m)
#pragma unroll
    for (int i = 0; i < 3; ++i) {
      int nt = 3 * wv + i;
      int sec = nt >> 2;
      int dcol = (nt & 3) * 16 + c;
      float bias = sec == 0 ? bq[dcol] : (sec == 1 ? bk[dcol] : bv[dcol]);
#pragma unroll
      for (int i2 = 0; i2 < 4; ++i2) {
        int rl = 16 * m + 4 * g + i2;
        float val = acc[m][i][i2] + bias;
        if (sec == 0) val *= qsc;
        if (sec < 2) elds[sec * 2048 + rl * 64 + dcol] = f2bf(val);
        else         elds[4096 + dcol * 32 + rl]       = f2bf(val);
      }
    }
  __syncthreads();
  // ---- contiguous 16B stores into fragment-native global layouts ----
  {
    int trow = t >> 3, d0 = (t & 7) * 8;           // q,k assignment
    s16x8 vq = *(const s16x8*)(elds + trow * 64 + d0);
    s16x8 vk = *(const s16x8*)(elds + 2048 + trow * 64 + d0);
    size_t offqk = (size_t)bb * (TT * DD) + (size_t)(tb >> 5) * 2048
                 + (d0 >> 4) * 512 + trow * 16 + (d0 & 15);
    *(s16x8*)(q_ws + offqk) = vq;
    *(s16x8*)(k_ws + offqk) = vk;
    int d = t >> 2, tq = (t & 3) * 8;              // v assignment
    s16x8 vvv = *(const s16x8*)(elds + 4096 + d * 32 + tq);
    int tg = tb + tq;
    size_t offv = (size_t)bb * (DD * TT) + (size_t)(tg >> 6) * 4096
                + (d >> 5) * 2048 + ((tg >> 4) & 3) * 512 + (d & 31) * 16 + (tg & 15);
    *(s16x8*)(vT_ws + offv) = vvv;
  }
}

// ---------------------------------------------------------------------------
// Kernel 2: fused flash attention + output projection.
// Grid 512 = 4 b x 128 q-tiles(32 rows); complementary pairing j32(s).
// 4 waves = 4-way KV parity.  K-prefetch double buffer + off-path softmax,
// per-mt exp/pack/stats for short live ranges (lets V loads hoist).
// ---------------------------------------------------------------------------
__global__ __launch_bounds__(256, 2) void attn_kernel(
    const unsigned short* __restrict__ q_ws, const unsigned short* __restrict__ k_ws,
    const unsigned short* __restrict__ vT_ws, const unsigned short* __restrict__ Wo_b,
    const float* __restrict__ bo, float* __restrict__ out)
{
  __shared__ float obuf[3 * 2048];          // waves 1-3 O^T          (24 KB)
  __shared__ float mstat[3 * 128];          // waves 1-3 m,l          (1.5 KB)
  __shared__ unsigned short clds[32 * 64];  // merged ctx bf16 [q][d] (4 KB)
  const int t = threadIdx.x, wv = t >> 6, lane = t & 63;
  const int qcol = lane & 31, h = lane >> 5;
  const int b = blockIdx.x & 3;
  const int jslot = blockIdx.x >> 2;
  const int j32 = (jslot < 64) ? (2 * jslot) : (127 - 2 * (jslot - 64));
  const int q0 = j32 * 32;
  const int L = j32 >> 1;                   // last KV tile (diagonal)
  const size_t base  = (size_t)b * TT * DD; // q,k frag space
  const size_t vbase = (size_t)b * DD * TT; // vT frag space
  const int g = lane >> 4, c = lane & 15;   // proj phase
  const int lchunk = (lane & 31) * 16 + (lane >> 5) * 8;   // frag lane offset

  // Q B-frags (contiguous 1KB per kk)
  s16x8 qf[4];
  {
    const unsigned short* qp = q_ws + base + (size_t)j32 * 2048;
#pragma unroll
    for (int kk = 0; kk < 4; ++kk) qf[kk] = *(const s16x8*)(qp + kk * 512 + lchunk);
  }
  f32x16 o[2];
#pragma unroll
  for (int mt = 0; mt < 2; ++mt)
#pragma unroll
    for (int rg = 0; rg < 16; ++rg) o[mt][rg] = 0.0f;
  float m_used = MNEG, l_run = 0.0f;
  bool first = true;

  auto loadK = [&](int kt, s16x8 (&kf)[2][4]) {
#pragma unroll
    for (int mt = 0; mt < 2; ++mt)
#pragma unroll
      for (int kk = 0; kk < 4; ++kk)
        kf[mt][kk] = *(const s16x8*)(k_ws + base +
                       (size_t)(2 * kt + mt) * 2048 + kk * 512 + lchunk);
  };

  auto tile = [&](int kt, s16x8 (&kf)[2][4], s16x8 (&kfn)[2][4]) {
    const int kv0 = kt * 64;
    // ---- S^T = K . Q^T ----
    f32x16 s[2];
#pragma unroll
    for (int mt = 0; mt < 2; ++mt)
#pragma unroll
      for (int rg = 0; rg < 16; ++rg) s[mt][rg] = 0.0f;
    __builtin_amdgcn_s_setprio(1);
#pragma unroll
    for (int kk = 0; kk < 4; ++kk)
#pragma unroll
      for (int mt = 0; mt < 2; ++mt)
        s[mt] = __builtin_amdgcn_mfma_f32_32x32x16_bf16(kf[mt][kk], qf[kk], s[mt], 0, 0, 0);
    __builtin_amdgcn_s_setprio(0);
    // ---- PREFETCH next parity tile's K ----
    if (kt + 4 <= L) loadK(kt + 4, kfn);
    // ---- V^T A-frags (independent; short live ranges below let these hoist)
    s16x8 vf[2][4];
#pragma unroll
    for (int mt = 0; mt < 2; ++mt)
#pragma unroll
      for (int ks = 0; ks < 4; ++ks)
        vf[mt][ks] = *(const s16x8*)(vT_ws + vbase +
                       (size_t)kt * 4096 + mt * 2048 + ks * 512 + lchunk);
    // ---- causal mask (diagonal tile only) ----
    if (kt == L) {
      int qq = q0 + qcol;
#pragma unroll
      for (int mt = 0; mt < 2; ++mt)
#pragma unroll
        for (int rg = 0; rg < 16; ++rg) {
          int kvabs = kv0 + 32 * mt + (rg & 3) + 8 * (rg >> 2) + 4 * h;
          if (kvabs > qq) s[mt][rg] = MNEG;
        }
    }
    // ---- first tile: establish per-row reference exactly (one-time chain) ----
    if (first) {
      first = false;
      float mx[16];
#pragma unroll
      for (int e = 0; e < 16; ++e) mx[e] = fmaxf(s[0][e], s[1][e]);
#pragma unroll
      for (int st = 8; st >= 1; st >>= 1)
#pragma unroll
        for (int e = 0; e < 8; ++e) if (e < st) mx[e] = fmaxf(mx[e], mx[e + st]);
      m_used = fmaxf(mx[0], __shfl_xor(mx[0], 32));
    }
    // ---- per-mt OFF-PATH exp + stats + pack (s[mt] dies at its pack) ----
    float psum = 0.0f, pmax = 0.0f;
    s16x8 pf[4];
#pragma unroll
    for (int mt = 0; mt < 2; ++mt) {
#pragma unroll
      for (int rg = 0; rg < 16; ++rg) s[mt][rg] = exp2f(s[mt][rg] - m_used);
      // inline row stats (tree over this mt's 16 values)
      float sm[8], mx2[8];
#pragma unroll
      for (int e = 0; e < 8; ++e) {
        sm[e]  = s[mt][e] + s[mt][e + 8];
        mx2[e] = fmaxf(s[mt][e], s[mt][e + 8]);
      }
#pragma unroll
      for (int st = 4; st >= 1; st >>= 1)
#pragma unroll
        for (int e = 0; e < 4; ++e)
          if (e < st) { sm[e] += sm[e + st]; mx2[e] = fmaxf(mx2[e], mx2[e + st]); }
      psum += sm[0];
      pmax = fmaxf(pmax, mx2[0]);
      // pack this mt's 16 values -> pf[2mt], pf[2mt+1]
      unsigned int a0 = cvtpk(s[mt][0],  s[mt][1]);
      unsigned int a1 = cvtpk(s[mt][2],  s[mt][3]);
      unsigned int b0 = cvtpk(s[mt][4],  s[mt][5]);
      unsigned int b1 = cvtpk(s[mt][6],  s[mt][7]);
      unsigned int c0 = cvtpk(s[mt][8],  s[mt][9]);
      unsigned int c1 = cvtpk(s[mt][10], s[mt][11]);
      unsigned int d0 = cvtpk(s[mt][12], s[mt][13]);
      unsigned int d1 = cvtpk(s[mt][14], s[mt][15]);
      asm("v_permlane32_swap_b32 %0, %1" : "+v"(a0), "+v"(b0));
      asm("v_permlane32_swap_b32 %0, %1" : "+v"(a1), "+v"(b1));
      asm("v_permlane32_swap_b32 %0, %1" : "+v"(c0), "+v"(d0));
      asm("v_permlane32_swap_b32 %0, %1" : "+v"(c1), "+v"(d1));
      pf[2 * mt]     = mk8(a0, a1, b0, b1);
      pf[2 * mt + 1] = mk8(c0, c1, d0, d1);
    }
    // ---- O^T += V^T . P^T ----
    __builtin_amdgcn_s_setprio(1);
#pragma unroll
    for (int ks = 0; ks < 4; ++ks)
#pragma unroll
      for (int mt = 0; mt < 2; ++mt)
        o[mt] = __builtin_amdgcn_mfma_f32_32x32x16_bf16(vf[mt][ks], pf[ks], o[mt], 0, 0, 0);
    __builtin_amdgcn_s_setprio(0);
    // ---- off-path bookkeeping (cross-half combine + rare rescale) ----
    float rowsum = psum + __shfl_xor(psum, 32);
    float mp = fmaxf(pmax, __shfl_xor(pmax, 32));
    l_run += rowsum;
    if (!__all(mp <= 256.0f)) {          // rare: reference drifted > 2^8
      float mpc = fmaxf(mp, 1.0f);       // only shrink rows that grew
      float dlt = log2f(mpc);
      float alpha = 1.0f / mpc;
      m_used += dlt;
      l_run *= alpha;
#pragma unroll
      for (int mt = 0; mt < 2; ++mt)
#pragma unroll
        for (int rg = 0; rg < 16; ++rg) o[mt][rg] *= alpha;
    }
  };

  // ---- pipelined KV loop (named double buffers; no runtime indexing) ----
  s16x8 kfA[2][4], kfB[2][4];
  int kt = wv;
  if (kt <= L) loadK(kt, kfA);
  while (kt <= L) {
    tile(kt, kfA, kfB);
    kt += 4;
    if (kt > L) break;
    tile(kt, kfB, kfA);
    kt += 4;
  }

  // ---- 4-way flash merge (wave 0 combines), ctx -> LDS bf16 [q][d] ----
  if (wv != 0) {
#pragma unroll
    for (int mt = 0; mt < 2; ++mt)
#pragma unroll
      for (int rg = 0; rg < 16; ++rg)
        obuf[(wv - 1) * 2048 + (mt * 16 + rg) * 64 + lane] = o[mt][rg];
    mstat[(wv - 1) * 128 + lane] = m_used;
    mstat[(wv - 1) * 128 + 64 + lane] = l_run;
  }
  __syncthreads();
  if (wv == 0) {
    float mB[3], lB[3];
    float mS = m_used;
#pragma unroll
    for (int i = 0; i < 3; ++i) {
      mB[i] = mstat[i * 128 + lane];
      lB[i] = mstat[i * 128 + 64 + lane];
      mS = fmaxf(mS, mB[i]);
    }
    float f0 = exp2f(m_used - mS);
    float fi[3];
    float l_tot = l_run * f0;
#pragma unroll
    for (int i = 0; i < 3; ++i) { fi[i] = exp2f(mB[i] - mS); l_tot += lB[i] * fi[i]; }
    float inv = 1.0f / l_tot;
#pragma unroll
    for (int mt = 0; mt < 2; ++mt) {
#pragma unroll
      for (int rgq = 0; rgq < 4; ++rgq) {
        s16x4 pb;
#pragma unroll
        for (int e = 0; e < 4; ++e) {
          int rg = 4 * rgq + e;
          float val = o[mt][rg] * f0;
#pragma unroll
          for (int i = 0; i < 3; ++i)
            val += obuf[i * 2048 + (mt * 16 + rg) * 64 + lane] * fi[i];
          pb[e] = (short)f2bf(val * inv);
        }
        int d0 = 32 * mt + 8 * rgq + 4 * h;
        int byte = qcol * 128 + d0 * 2;
        *(s16x4*)((char*)clds + (byte ^ swzK(qcol))) = pb;
      }
    }
  }
  __syncthreads();

  // ---- fused output projection: out[q0..q0+32) x 1024 = ctx(32x64) . Wo^T ----
  s16x8 afr[2][2];
#pragma unroll
  for (int mt = 0; mt < 2; ++mt)
#pragma unroll
    for (int kk = 0; kk < 2; ++kk) {
      int ra = 16 * mt + c;
      afr[mt][kk] = *(const s16x8*)((char*)clds +
                      ((ra * 128 + (32 * kk + 8 * g) * 2) ^ swzK(ra)));
    }
  const int wchunk = (lane & 15) * 32 + (lane >> 4) * 8;   // Wo_b frag lane offset
  const size_t orow0 = (size_t)(b * TT + q0);
#pragma unroll 4
  for (int nt = 0; nt < 16; ++nt) {
    int col = wv * 256 + 16 * nt + c;
    s16x8 bfr[2];
#pragma unroll
    for (int kk = 0; kk < 2; ++kk)
      bfr[kk] = *(const s16x8*)(Wo_b + (size_t)(wv * 16 + nt) * 1024
                                + kk * 512 + wchunk);
    f32x4 acc4[2];
#pragma unroll
    for (int mt = 0; mt < 2; ++mt)
#pragma unroll
      for (int e = 0; e < 4; ++e) acc4[mt][e] = 0.0f;
#pragma unroll
    for (int kk = 0; kk < 2; ++kk)
#pragma unroll
      for (int mt = 0; mt < 2; ++mt)
        acc4[mt] = __builtin_amdgcn_mfma_f32_16x16x32_bf16(afr[mt][kk], bfr[kk],
                                                           acc4[mt], 0, 0, 0);
    float bias = bo[col];
#pragma unroll
    for (int mt = 0; mt < 2; ++mt)
#pragma unroll
      for (int i = 0; i < 4; ++i) {
        size_t row = orow0 + 16 * mt + 4 * g + i;
        out[row * HH + col] = acc4[mt][i] + bias;
      }
  }
}

// ---------------------------------------------------------------------------
extern "C" void kernel_launch(void* const* d_in, const int* in_sizes, int n_in,
                              void* d_out, int out_size, void* d_ws, size_t ws_size,
                              hipStream_t stream)
{
  const float* y  = (const float*)d_in[0];
  const float* Wq = (const float*)d_in[1];
  const float* bq = (const float*)d_in[2];
  const float* Wk = (const float*)d_in[3];
  const float* bk = (const float*)d_in[4];
  const float* Wv = (const float*)d_in[5];
  const float* bv = (const float*)d_in[6];
  const float* Wo = (const float*)d_in[7];
  const float* bo = (const float*)d_in[8];
  float* out = (float*)d_out;
  char* ws = (char*)d_ws;
  // workspace layout (bytes) — total 6,815,744 (6.5 MiB)
  unsigned short* Wall  = (unsigned short*)(ws);                        // 384 KiB
  unsigned short* Wo_b  = (unsigned short*)(ws + 393216);               // 128 KiB
  unsigned short* q_ws  = (unsigned short*)(ws + 524288);               // 2 MiB
  unsigned short* k_ws  = (unsigned short*)(ws + 524288 + 2097152);     // 2 MiB
  unsigned short* vT_ws = (unsigned short*)(ws + 524288 + 2 * 2097152); // 2 MiB

  prep_kernel<<<dim3(256), dim3(256), 0, stream>>>(Wq, Wk, Wv, Wo, Wall, Wo_b);
  qkv_kernel<<<dim3(512), dim3(256), 0, stream>>>(y, Wall, bq, bk, bv, q_ws, k_ws, vT_ws);
  attn_kernel<<<dim3(512), dim3(256), 0, stream>>>(q_ws, k_ws, vT_ws, Wo_b, bo, out);
}